// Round 1
// baseline (3296.870 us; speedup 1.0000x reference)
//
#include <hip/hip_runtime.h>
#include <math.h>

#define SS 128
#define BB 32
#define CC 16
#define DW 256
#define DC 64
#define HC 128
#define KX 384   // DW + HC
#define TT 17

__device__ __forceinline__ float sigf(float x) { return 1.0f / (1.0f + __expf(-x)); }

// ---------------------------------------------------------------- grid barrier
__device__ __forceinline__ void grid_barrier(unsigned int* bar, unsigned int nwg) {
  __threadfence();            // each thread: flush its stores (agent scope)
  __syncthreads();
  if (threadIdx.x == 0) {
    unsigned int g = __hip_atomic_load(&bar[1], __ATOMIC_RELAXED, __HIP_MEMORY_SCOPE_AGENT);
    unsigned int a = __hip_atomic_fetch_add(&bar[0], 1u, __ATOMIC_ACQ_REL, __HIP_MEMORY_SCOPE_AGENT);
    if (a == nwg - 1u) {
      __hip_atomic_store(&bar[0], 0u, __ATOMIC_RELAXED, __HIP_MEMORY_SCOPE_AGENT);
      __hip_atomic_store(&bar[1], g + 1u, __ATOMIC_RELEASE, __HIP_MEMORY_SCOPE_AGENT);
    } else {
      while (__hip_atomic_load(&bar[1], __ATOMIC_ACQUIRE, __HIP_MEMORY_SCOPE_AGENT) == g) {
        __builtin_amdgcn_s_sleep(8);
      }
    }
  }
  __syncthreads();
  __threadfence();            // each thread: invalidate stale cached lines
}

// ---------------------------------------------------------------- K0: char ih vocab table
// ihv[(d*100+v)*256 + g] = c_b_d[g] + sum_k W_ce[v,k] * c_Wih_d[g,k]
__global__ __launch_bounds__(256) void k0_ihvocab(
    const float* __restrict__ Wce,
    const float* __restrict__ WihF, const float* __restrict__ bF,
    const float* __restrict__ WihB, const float* __restrict__ bB,
    float* __restrict__ ihv) {
  int blk = blockIdx.x;          // 0..199
  int d = blk / 100, v = blk % 100;
  const float* Wih = d ? WihB : WihF;
  const float* bb  = d ? bB   : bF;
  __shared__ float ce[DC];
  if (threadIdx.x < DC) ce[threadIdx.x] = Wce[v * DC + threadIdx.x];
  __syncthreads();
  int g = threadIdx.x;
  float acc = bb[g];
  #pragma unroll 16
  for (int k = 0; k < DC; ++k) acc += ce[k] * Wih[g * DC + k];
  ihv[(d * 100 + v) * 256 + g] = acc;
}

// ---------------------------------------------------------------- K1: char BiLSTM (per-chain, no global sync)
// 512 blocks: d = blk>>8, 16 chains each. Whh resident in LDS. Writes final h into x[:, d*64 .. ]
__global__ __launch_bounds__(256) void k1_char(
    const int* __restrict__ charidx,   // (B,S,C)
    const float* __restrict__ WhhF, const float* __restrict__ WhhB,
    const float* __restrict__ ihv,     // (2,100,256)
    float* __restrict__ x)             // (4096, 384)
{
  int blk = blockIdx.x;
  int d = blk >> 8;
  int n0 = (blk & 255) * 16;
  const float* Whh = d ? WhhB : WhhF;

  __shared__ float Wl[256 * 68];   // [g][k], stride 68 (16B aligned rows)
  __shared__ float hl[16 * 68];    // [ln][k]

  for (int i = threadIdx.x; i < 256 * 64; i += 256) {
    int g = i >> 6, k = i & 63;
    Wl[g * 68 + k] = Whh[i];
  }
  __syncthreads();

  int hh = threadIdx.x & 63;
  int ng = threadIdx.x >> 6;   // 0..3
  float c[4] = {0.f, 0.f, 0.f, 0.f};
  float h[4] = {0.f, 0.f, 0.f, 0.f};
  int bb_[4], ss_[4];
  #pragma unroll
  for (int m = 0; m < 4; ++m) {
    int n = n0 + ng + 4 * m;
    bb_[m] = n >> 7; ss_[m] = n & 127;
  }

  for (int t = 0; t < CC; ++t) {
    int cpos = d ? (CC - 1 - t) : t;
    float acc[4][4];
    #pragma unroll
    for (int m = 0; m < 4; ++m) {
      int v = charidx[bb_[m] * (SS * CC) + ss_[m] * CC + cpos];
      const float* base = ihv + (d * 100 + v) * 256 + hh;
      acc[m][0] = base[0]; acc[m][1] = base[64]; acc[m][2] = base[128]; acc[m][3] = base[192];
    }
    if (t > 0) {
      #pragma unroll 4
      for (int k = 0; k < 64; k += 4) {
        float4 w4[4];
        #pragma unroll
        for (int q = 0; q < 4; ++q)
          w4[q] = *(const float4*)&Wl[(q * 64 + hh) * 68 + k];
        #pragma unroll
        for (int m = 0; m < 4; ++m) {
          float4 h4 = *(const float4*)&hl[(ng + 4 * m) * 68 + k];
          #pragma unroll
          for (int q = 0; q < 4; ++q)
            acc[m][q] += h4.x * w4[q].x + h4.y * w4[q].y + h4.z * w4[q].z + h4.w * w4[q].w;
        }
      }
      __syncthreads();   // done reading hl before overwrite
    }
    #pragma unroll
    for (int m = 0; m < 4; ++m) {
      float ig = sigf(acc[m][0]);
      float fg = sigf(acc[m][1]);
      float gg = tanhf(acc[m][2]);
      float og = sigf(acc[m][3]);
      c[m] = fg * c[m] + ig * gg;
      h[m] = og * tanhf(c[m]);
      hl[(ng + 4 * m) * 68 + hh] = h[m];
    }
    __syncthreads();
  }
  #pragma unroll
  for (int m = 0; m < 4; ++m) {
    int row = ss_[m] * BB + bb_[m];
    x[row * KX + d * 64 + hh] = h[m];
  }
}

// ---------------------------------------------------------------- K2: word embedding gather
__global__ __launch_bounds__(64) void k2_we(
    const int* __restrict__ sentence, const float* __restrict__ Wwe,
    float* __restrict__ x) {
  int row = blockIdx.x;                 // s*32+b
  int idx = sentence[row];              // sentence is (S,B) row-major
  const float4* src = (const float4*)(Wwe + (size_t)idx * DW);
  float4* dst = (float4*)(x + (size_t)row * KX + HC);
  dst[threadIdx.x] = src[threadIdx.x];  // 64 * 16B = 1KB
}

// ---------------------------------------------------------------- K3: word ih GEMM  wg[d][row][g]
// (4096 x 384) @ (384 x 1024) per dir. 128x128 tiles, BK=32, 8x8 micro.
__global__ __launch_bounds__(256) void k3_ihgemm(
    const float* __restrict__ x,
    const float* __restrict__ WihF, const float* __restrict__ bF,
    const float* __restrict__ WihB, const float* __restrict__ bB,
    float* __restrict__ wg) {
  int n0 = blockIdx.x * 128;           // 0..1920 over 2048 = 2 dirs * 1024
  int m0 = blockIdx.y * 128;
  int d  = n0 >> 10;
  int gb = n0 & 1023;
  const float* Wih  = d ? WihB : WihF;
  const float* bias = d ? bB   : bF;

  __shared__ float At[32][132];        // [k][m]
  __shared__ float Bt[32][132];        // [k][n]

  int tid = threadIdx.x;
  int half = tid & 1, r = tid >> 1;    // r: 0..127
  int tm = tid & 15, tn = tid >> 4;
  float acc[8][8] = {};

  for (int k0 = 0; k0 < KX; k0 += 32) {
    __syncthreads();
    {
      const float4* srcA = (const float4*)(x + (size_t)(m0 + r) * KX + k0 + half * 16);
      const float4* srcB = (const float4*)(Wih + (size_t)(gb + r) * KX + k0 + half * 16);
      #pragma unroll
      for (int q = 0; q < 4; ++q) {
        float4 v = srcA[q];
        int kk = half * 16 + q * 4;
        At[kk + 0][r] = v.x; At[kk + 1][r] = v.y; At[kk + 2][r] = v.z; At[kk + 3][r] = v.w;
      }
      #pragma unroll
      for (int q = 0; q < 4; ++q) {
        float4 v = srcB[q];
        int kk = half * 16 + q * 4;
        Bt[kk + 0][r] = v.x; Bt[kk + 1][r] = v.y; Bt[kk + 2][r] = v.z; Bt[kk + 3][r] = v.w;
      }
    }
    __syncthreads();
    #pragma unroll 8
    for (int k = 0; k < 32; ++k) {
      float4 a0 = *(const float4*)&At[k][tm * 8];
      float4 a1 = *(const float4*)&At[k][tm * 8 + 4];
      float4 b0 = *(const float4*)&Bt[k][tn * 8];
      float4 b1 = *(const float4*)&Bt[k][tn * 8 + 4];
      float av[8] = {a0.x, a0.y, a0.z, a0.w, a1.x, a1.y, a1.z, a1.w};
      float bv[8] = {b0.x, b0.y, b0.z, b0.w, b1.x, b1.y, b1.z, b1.w};
      #pragma unroll
      for (int i = 0; i < 8; ++i)
        #pragma unroll
        for (int jq = 0; jq < 8; ++jq)
          acc[i][jq] += av[i] * bv[jq];
    }
  }
  float bv8[8];
  #pragma unroll
  for (int jq = 0; jq < 8; ++jq) bv8[jq] = bias[gb + tn * 8 + jq];
  #pragma unroll
  for (int i = 0; i < 8; ++i) {
    int m = m0 + tm * 8 + i;
    float* dst = wg + ((size_t)(d * 4096 + m)) * 1024 + gb + tn * 8;
    float4 v0 = {acc[i][0] + bv8[0], acc[i][1] + bv8[1], acc[i][2] + bv8[2], acc[i][3] + bv8[3]};
    float4 v1 = {acc[i][4] + bv8[4], acc[i][5] + bv8[5], acc[i][6] + bv8[6], acc[i][7] + bv8[7]};
    *(float4*)dst = v0; *(float4*)(dst + 4) = v1;
  }
}

// ---------------------------------------------------------------- K4: word BiLSTM persistent recurrence
// 64 WGs (32/dir). WG w owns h-indices j0..j0+8 (all 4 gates). Whh slice in LDS.
__global__ __launch_bounds__(256) void k4_word(
    const float* __restrict__ WhhF, const float* __restrict__ WhhB,
    const float* __restrict__ wg,     // (2,4096,1024)
    float* __restrict__ outh,         // (4096,512)
    float* __restrict__ hbuf,         // (2 dir, 2 parity, 256*32) [k*32+b]
    unsigned int* __restrict__ bar) {
  int blk = blockIdx.x;
  int d = blk >> 5;
  int w = blk & 31;
  int j0 = w * 8;
  const float* Whh = d ? WhhB : WhhF;

  __shared__ float Wl[32 * 260];   // [lr][k], lr = q*8+jj
  __shared__ float hl[32 * 260];   // [b][k]

  for (int i = threadIdx.x; i < 32 * 256; i += 256) {
    int lr = i >> 8, k = i & 255;
    int R = (lr >> 3) * 256 + j0 + (lr & 7);
    Wl[lr * 260 + k] = Whh[R * 256 + k];
  }
  __syncthreads();

  int b  = threadIdx.x & 31;
  int jj = threadIdx.x >> 5;   // 0..7
  float c = 0.f;

  for (int t = 0; t < SS; ++t) {
    int s = d ? (SS - 1 - t) : t;
    const float* ihp = wg + ((size_t)(d * 4096) + s * 32 + b) * 1024 + j0 + jj;
    float g0 = ihp[0], g1 = ihp[256], g2 = ihp[512], g3 = ihp[768];
    if (t > 0) {
      int p = t & 1;   // parity written by previous step
      const float* hb = hbuf + (size_t)(d * 2 + p) * 8192;
      for (int i = threadIdx.x; i < 8192; i += 256) {
        int k = i >> 5, b2 = i & 31;
        hl[b2 * 260 + k] = hb[i];
      }
      __syncthreads();
      #pragma unroll 8
      for (int k = 0; k < 256; k += 4) {
        float4 h4 = *(const float4*)&hl[b * 260 + k];
        float4 w0 = *(const float4*)&Wl[(0 * 8 + jj) * 260 + k];
        float4 w1 = *(const float4*)&Wl[(1 * 8 + jj) * 260 + k];
        float4 w2 = *(const float4*)&Wl[(2 * 8 + jj) * 260 + k];
        float4 w3 = *(const float4*)&Wl[(3 * 8 + jj) * 260 + k];
        g0 += h4.x * w0.x + h4.y * w0.y + h4.z * w0.z + h4.w * w0.w;
        g1 += h4.x * w1.x + h4.y * w1.y + h4.z * w1.z + h4.w * w1.w;
        g2 += h4.x * w2.x + h4.y * w2.y + h4.z * w2.z + h4.w * w2.w;
        g3 += h4.x * w3.x + h4.y * w3.y + h4.z * w3.z + h4.w * w3.w;
      }
    }
    float ig = sigf(g0), fg = sigf(g1), gg = tanhf(g2), og = sigf(g3);
    c = fg * c + ig * gg;
    float h = og * tanhf(c);
    outh[(size_t)(s * 32 + b) * 512 + d * 256 + j0 + jj] = h;
    int wp = (t & 1) ^ 1;
    hbuf[(size_t)(d * 2 + wp) * 8192 + (j0 + jj) * 32 + b] = h;
    if (t < SS - 1) grid_barrier(bar, 64);
  }
}

// ---------------------------------------------------------------- K5: emit GEMM (tiny)
__global__ __launch_bounds__(64) void k5_emit(
    const float* __restrict__ outh, const float* __restrict__ eW,
    const float* __restrict__ eb, float* __restrict__ em) {
  int row = blockIdx.x;
  int t = threadIdx.x;
  if (t < TT) {
    const float4* o4 = (const float4*)(outh + (size_t)row * 512);
    const float4* w4 = (const float4*)(eW + (size_t)t * 512);
    float acc = 0.f;
    #pragma unroll 16
    for (int k = 0; k < 128; ++k) {
      float4 a = o4[k], bq = w4[k];
      acc += a.x * bq.x + a.y * bq.y + a.z * bq.z + a.w * bq.w;
    }
    em[row * TT + t] = acc + eb[t];
  }
}

// ---------------------------------------------------------------- K6: CRF NLL (32 independent batches)
__global__ __launch_bounds__(64) void k6_crf(
    const int* __restrict__ sentence, const int* __restrict__ tags,
    const float* __restrict__ em, const float* __restrict__ trans,
    const float* __restrict__ startv, const float* __restrict__ endv,
    float* __restrict__ outp) {
  int b = blockIdx.x;
  int j = threadIdx.x;
  __shared__ float ash[TT];
  __shared__ float red[TT];
  float tc[TT];
  float alpha = 0.f;
  if (j < TT) {
    #pragma unroll
    for (int i = 0; i < TT; ++i) tc[i] = trans[i * TT + j];
    alpha = startv[j] + em[(0 * BB + b) * TT + j];
  }
  for (int s = 1; s < SS; ++s) {
    if (j < TT) ash[j] = alpha;
    __syncthreads();
    int m = (sentence[s * BB + b] != 1) ? 1 : 0;
    if (j < TT) {
      float mx = -1e30f;
      #pragma unroll
      for (int i = 0; i < TT; ++i) mx = fmaxf(mx, ash[i] + tc[i]);
      float sum = 0.f;
      #pragma unroll
      for (int i = 0; i < TT; ++i) sum += __expf(ash[i] + tc[i] - mx);
      float nxt = mx + __logf(sum) + em[(s * BB + b) * TT + j];
      if (m) alpha = nxt;
    }
    __syncthreads();
  }
  if (j < TT) red[j] = alpha + endv[j];
  __syncthreads();
  if (j == 0) {
    float mx = -1e30f;
    for (int i = 0; i < TT; ++i) mx = fmaxf(mx, red[i]);
    float sum = 0.f;
    for (int i = 0; i < TT; ++i) sum += __expf(red[i] - mx);
    float den = mx + __logf(sum);
    int prev = tags[0 * BB + b];
    float num = startv[prev] + em[(0 * BB + b) * TT + prev];
    for (int s = 1; s < SS; ++s) {
      int tg = tags[s * BB + b];
      if (sentence[s * BB + b] != 1) {
        num += trans[prev * TT + tg] + em[(s * BB + b) * TT + tg];
        prev = tg;
      }
    }
    num += endv[prev];
    atomicAdd(outp, den - num);
  }
}

// ---------------------------------------------------------------- launcher
extern "C" void kernel_launch(void* const* d_in, const int* in_sizes, int n_in,
                              void* d_out, int out_size, void* d_ws, size_t ws_size,
                              hipStream_t stream) {
  (void)in_sizes; (void)n_in; (void)out_size; (void)ws_size;
  const int*   sentence = (const int*)d_in[0];
  const int*   charidx  = (const int*)d_in[1];
  const int*   tags     = (const int*)d_in[2];
  const float* Wwe   = (const float*)d_in[3];
  const float* Wce   = (const float*)d_in[4];
  const float* cWihF = (const float*)d_in[5];
  const float* cWhhF = (const float*)d_in[6];
  const float* cbF   = (const float*)d_in[7];
  const float* wWihF = (const float*)d_in[8];
  const float* wWhhF = (const float*)d_in[9];
  const float* wbF   = (const float*)d_in[10];
  const float* cWihB = (const float*)d_in[11];
  const float* cWhhB = (const float*)d_in[12];
  const float* cbB   = (const float*)d_in[13];
  const float* wWihB = (const float*)d_in[14];
  const float* wWhhB = (const float*)d_in[15];
  const float* wbB   = (const float*)d_in[16];
  const float* eW    = (const float*)d_in[17];
  const float* eb    = (const float*)d_in[18];
  const float* trans = (const float*)d_in[19];
  const float* startv= (const float*)d_in[20];
  const float* endv  = (const float*)d_in[21];

  char* ws = (char*)d_ws;
  unsigned int* bar = (unsigned int*)(ws + 0);            //    256 B
  float* ihv  = (float*)(ws + 256);                       // 204800 B
  float* x    = (float*)(ws + 205056);                    // 6291456 B
  float* wg   = (float*)(ws + 6496512);                   // 33554432 B
  float* hbuf = (float*)(ws + 40050944);                  // 131072 B
  float* outh = (float*)(ws + 40182016);                  // 8388608 B
  float* em   = (float*)(ws + 48570624);                  // 278528 B
  // total ws usage: 48,849,152 B

  hipMemsetAsync(bar, 0, 256, stream);
  hipMemsetAsync(d_out, 0, sizeof(float), stream);

  k0_ihvocab<<<200, 256, 0, stream>>>(Wce, cWihF, cbF, cWihB, cbB, ihv);
  k1_char<<<512, 256, 0, stream>>>(charidx, cWhhF, cWhhB, ihv, x);
  k2_we<<<4096, 64, 0, stream>>>(sentence, Wwe, x);
  k3_ihgemm<<<dim3(16, 32), 256, 0, stream>>>(x, wWihF, wbF, wWihB, wbB, wg);
  k4_word<<<64, 256, 0, stream>>>(wWhhF, wWhhB, wg, outh, hbuf, bar);
  k5_emit<<<4096, 64, 0, stream>>>(outh, eW, eb, em);
  k6_crf<<<32, 64, 0, stream>>>(sentence, tags, em, trans, startv, endv, (float*)d_out);
}

// Round 2
// 1315.318 us; speedup vs baseline: 2.5065x; 2.5065x over previous
//
#include <hip/hip_runtime.h>
#include <math.h>

#define SS 128
#define BB 32
#define CC 16
#define DW 256
#define DC 64
#define HC 128
#define KX 384   // DW + HC
#define TT 17

typedef __attribute__((ext_vector_type(8))) short bf16x8;
typedef __attribute__((ext_vector_type(4))) float f32x4;
typedef unsigned long long ull_t;

__device__ __forceinline__ float sigf(float x) { return 1.0f / (1.0f + __expf(-x)); }
__device__ __forceinline__ float tanhfast(float x) {
  float xc = fminf(fmaxf(x, -15.f), 15.f);
  float e = __expf(2.f * xc);
  return (e - 1.f) / (e + 1.f);
}
__device__ __forceinline__ unsigned short f2bf(float x) {
  unsigned int u = __float_as_uint(x);
  u += 0x7FFF + ((u >> 16) & 1);
  return (unsigned short)(u >> 16);
}
// LLC-coherent (agent-scope) accessors: compile to global ops with sc bits set,
// bypassing the non-cross-XCD-coherent L1/L2 — no cache-wide fences needed.
__device__ __forceinline__ void st_flag(unsigned int* p, unsigned int v) {
  __hip_atomic_store(p, v, __ATOMIC_RELEASE, __HIP_MEMORY_SCOPE_AGENT);
}
__device__ __forceinline__ ull_t ld_ull(const ull_t* p) {
  return __hip_atomic_load(p, __ATOMIC_RELAXED, __HIP_MEMORY_SCOPE_AGENT);
}
__device__ __forceinline__ void st_ushort(unsigned short* p, unsigned short v) {
  __hip_atomic_store(p, v, __ATOMIC_RELAXED, __HIP_MEMORY_SCOPE_AGENT);
}

// ---------------------------------------------------------------- K0: char ih vocab table
__global__ __launch_bounds__(256) void k0_ihvocab(
    const float* __restrict__ Wce,
    const float* __restrict__ WihF, const float* __restrict__ bF,
    const float* __restrict__ WihB, const float* __restrict__ bB,
    float* __restrict__ ihv) {
  int blk = blockIdx.x;          // 0..199
  int d = blk / 100, v = blk % 100;
  const float* Wih = d ? WihB : WihF;
  const float* bb  = d ? bB   : bF;
  __shared__ float ce[DC];
  if (threadIdx.x < DC) ce[threadIdx.x] = Wce[v * DC + threadIdx.x];
  __syncthreads();
  int g = threadIdx.x;
  float acc = bb[g];
  #pragma unroll 16
  for (int k = 0; k < DC; ++k) acc += ce[k] * Wih[g * DC + k];
  ihv[(d * 100 + v) * 256 + g] = acc;
}

// ---------------------------------------------------------------- K1: char BiLSTM (per-chain, no global sync)
__global__ __launch_bounds__(256) void k1_char(
    const int* __restrict__ charidx,   // (B,S,C)
    const float* __restrict__ WhhF, const float* __restrict__ WhhB,
    const float* __restrict__ ihv,     // (2,100,256)
    float* __restrict__ x)             // (4096, 384)
{
  int blk = blockIdx.x;
  int d = blk >> 8;
  int n0 = (blk & 255) * 16;
  const float* Whh = d ? WhhB : WhhF;

  __shared__ float Wl[256 * 68];
  __shared__ float hl[16 * 68];

  for (int i = threadIdx.x; i < 256 * 64; i += 256) {
    int g = i >> 6, k = i & 63;
    Wl[g * 68 + k] = Whh[i];
  }
  __syncthreads();

  int hh = threadIdx.x & 63;
  int ng = threadIdx.x >> 6;
  float c[4] = {0.f, 0.f, 0.f, 0.f};
  float h[4] = {0.f, 0.f, 0.f, 0.f};
  int bb_[4], ss_[4];
  #pragma unroll
  for (int m = 0; m < 4; ++m) {
    int n = n0 + ng + 4 * m;
    bb_[m] = n >> 7; ss_[m] = n & 127;
  }

  for (int t = 0; t < CC; ++t) {
    int cpos = d ? (CC - 1 - t) : t;
    float acc[4][4];
    #pragma unroll
    for (int m = 0; m < 4; ++m) {
      int v = charidx[bb_[m] * (SS * CC) + ss_[m] * CC + cpos];
      const float* base = ihv + (d * 100 + v) * 256 + hh;
      acc[m][0] = base[0]; acc[m][1] = base[64]; acc[m][2] = base[128]; acc[m][3] = base[192];
    }
    if (t > 0) {
      #pragma unroll 4
      for (int k = 0; k < 64; k += 4) {
        float4 w4[4];
        #pragma unroll
        for (int q = 0; q < 4; ++q)
          w4[q] = *(const float4*)&Wl[(q * 64 + hh) * 68 + k];
        #pragma unroll
        for (int m = 0; m < 4; ++m) {
          float4 h4 = *(const float4*)&hl[(ng + 4 * m) * 68 + k];
          #pragma unroll
          for (int q = 0; q < 4; ++q)
            acc[m][q] += h4.x * w4[q].x + h4.y * w4[q].y + h4.z * w4[q].z + h4.w * w4[q].w;
        }
      }
      __syncthreads();
    }
    #pragma unroll
    for (int m = 0; m < 4; ++m) {
      float ig = sigf(acc[m][0]);
      float fg = sigf(acc[m][1]);
      float gg = tanhfast(acc[m][2]);
      float og = sigf(acc[m][3]);
      c[m] = fg * c[m] + ig * gg;
      h[m] = og * tanhfast(c[m]);
      hl[(ng + 4 * m) * 68 + hh] = h[m];
    }
    __syncthreads();
  }
  #pragma unroll
  for (int m = 0; m < 4; ++m) {
    int row = ss_[m] * BB + bb_[m];
    x[row * KX + d * 64 + hh] = h[m];
  }
}

// ---------------------------------------------------------------- K2: word embedding gather
__global__ __launch_bounds__(64) void k2_we(
    const int* __restrict__ sentence, const float* __restrict__ Wwe,
    float* __restrict__ x) {
  int row = blockIdx.x;
  int idx = sentence[row];
  const float4* src = (const float4*)(Wwe + (size_t)idx * DW);
  float4* dst = (float4*)(x + (size_t)row * KX + HC);
  dst[threadIdx.x] = src[threadIdx.x];
}

// ---------------------------------------------------------------- K3: word ih GEMM  wg[d][row][g]
__global__ __launch_bounds__(256) void k3_ihgemm(
    const float* __restrict__ x,
    const float* __restrict__ WihF, const float* __restrict__ bF,
    const float* __restrict__ WihB, const float* __restrict__ bB,
    float* __restrict__ wg) {
  int n0 = blockIdx.x * 128;
  int m0 = blockIdx.y * 128;
  int d  = n0 >> 10;
  int gb = n0 & 1023;
  const float* Wih  = d ? WihB : WihF;
  const float* bias = d ? bB   : bF;

  __shared__ float At[32][132];
  __shared__ float Bt[32][132];

  int tid = threadIdx.x;
  int half = tid & 1, r = tid >> 1;
  int tm = tid & 15, tn = tid >> 4;
  float acc[8][8] = {};

  for (int k0 = 0; k0 < KX; k0 += 32) {
    __syncthreads();
    {
      const float4* srcA = (const float4*)(x + (size_t)(m0 + r) * KX + k0 + half * 16);
      const float4* srcB = (const float4*)(Wih + (size_t)(gb + r) * KX + k0 + half * 16);
      #pragma unroll
      for (int q = 0; q < 4; ++q) {
        float4 v = srcA[q];
        int kk = half * 16 + q * 4;
        At[kk + 0][r] = v.x; At[kk + 1][r] = v.y; At[kk + 2][r] = v.z; At[kk + 3][r] = v.w;
      }
      #pragma unroll
      for (int q = 0; q < 4; ++q) {
        float4 v = srcB[q];
        int kk = half * 16 + q * 4;
        Bt[kk + 0][r] = v.x; Bt[kk + 1][r] = v.y; Bt[kk + 2][r] = v.z; Bt[kk + 3][r] = v.w;
      }
    }
    __syncthreads();
    #pragma unroll 8
    for (int k = 0; k < 32; ++k) {
      float4 a0 = *(const float4*)&At[k][tm * 8];
      float4 a1 = *(const float4*)&At[k][tm * 8 + 4];
      float4 b0 = *(const float4*)&Bt[k][tn * 8];
      float4 b1 = *(const float4*)&Bt[k][tn * 8 + 4];
      float av[8] = {a0.x, a0.y, a0.z, a0.w, a1.x, a1.y, a1.z, a1.w};
      float bv[8] = {b0.x, b0.y, b0.z, b0.w, b1.x, b1.y, b1.z, b1.w};
      #pragma unroll
      for (int i = 0; i < 8; ++i)
        #pragma unroll
        for (int jq = 0; jq < 8; ++jq)
          acc[i][jq] += av[i] * bv[jq];
    }
  }
  float bv8[8];
  #pragma unroll
  for (int jq = 0; jq < 8; ++jq) bv8[jq] = bias[gb + tn * 8 + jq];
  #pragma unroll
  for (int i = 0; i < 8; ++i) {
    int m = m0 + tm * 8 + i;
    float* dst = wg + ((size_t)(d * 4096 + m)) * 1024 + gb + tn * 8;
    float4 v0 = {acc[i][0] + bv8[0], acc[i][1] + bv8[1], acc[i][2] + bv8[2], acc[i][3] + bv8[3]};
    float4 v1 = {acc[i][4] + bv8[4], acc[i][5] + bv8[5], acc[i][6] + bv8[6], acc[i][7] + bv8[7]};
    *(float4*)dst = v0; *(float4*)(dst + 4) = v1;
  }
}

// ---------------------------------------------------------------- K4: word BiLSTM, MFMA + distributed flags
// 8 WGs: 4 per direction. Wave wv of WG w owns h-indices j0w..j0w+15 (x4 gate blocks).
// Whh slice lives in 128 VGPRs/lane as bf16 B-fragments. h exchanged via LLC (agent-scope).
__global__ __launch_bounds__(256, 1) void k4_word(
    const float* __restrict__ WhhF, const float* __restrict__ WhhB,
    const float* __restrict__ wg,           // (2,4096,1024) f32
    float* __restrict__ outh,               // (4096,512) f32
    unsigned short* __restrict__ hbuf,      // (2 dir, 2 parity, 32 b, 256 k) bf16
    unsigned int* __restrict__ flags) {     // per dir: 4 uints at dir*64
  const int blk = blockIdx.x;               // 0..7
  const int d = blk >> 2, w = blk & 3;
  const int tid = threadIdx.x;
  const int wv = tid >> 6, l = tid & 63;
  const int l15 = l & 15, q4 = l >> 4;      // q4 = lane quad 0..3
  const int j0w = w * 64 + wv * 16;
  const float* __restrict__ Whh = d ? WhhB : WhhF;
  unsigned short* hb_d = hbuf + d * 16384;  // 2 parities * 8192
  unsigned int* fl = flags + d * 64;

  // ---- Whh B-fragments resident in registers: Bf[q][ks], lane holds
  // B[k=ks*32+q4*8+j][n=l15] = Whh[q*256 + j0w + l15][k]
  bf16x8 Bf[4][8];
  #pragma unroll
  for (int q = 0; q < 4; ++q) {
    const float* wr = Whh + (size_t)(q * 256 + j0w + l15) * 256 + q4 * 8;
    #pragma unroll
    for (int ks = 0; ks < 8; ++ks) {
      float4 lo = *(const float4*)(wr + ks * 32);
      float4 hi = *(const float4*)(wr + ks * 32 + 4);
      bf16x8 f;
      f[0] = (short)f2bf(lo.x); f[1] = (short)f2bf(lo.y);
      f[2] = (short)f2bf(lo.z); f[3] = (short)f2bf(lo.w);
      f[4] = (short)f2bf(hi.x); f[5] = (short)f2bf(hi.y);
      f[6] = (short)f2bf(hi.z); f[7] = (short)f2bf(hi.w);
      Bf[q][ks] = f;
    }
  }

  float cst[8];
  #pragma unroll
  for (int i = 0; i < 8; ++i) cst[i] = 0.f;

  for (int t = 0; t < SS; ++t) {
    const int s = d ? (SS - 1 - t) : t;

    // ---- ih gates into MFMA C-layout: acc[q][mt][r] = wg gate for
    // batch b = q4*4 + r + mt*16, gate col q*256 + j0w + l15  (issued early)
    f32x4 acc[4][2];
    const float* wgs = wg + ((size_t)d * 4096 + (size_t)s * 32) * 1024 + j0w + l15;
    #pragma unroll
    for (int q = 0; q < 4; ++q)
      #pragma unroll
      for (int mt = 0; mt < 2; ++mt)
        #pragma unroll
        for (int r = 0; r < 4; ++r)
          acc[q][mt][r] = wgs[(size_t)(q4 * 4 + r + mt * 16) * 1024 + q * 256];

    if (t > 0) {
      if (tid == 0) {
        for (;;) {
          ull_t p0 = ld_ull((const ull_t*)fl);
          ull_t p1 = ld_ull((const ull_t*)fl + 1);
          unsigned int a0 = (unsigned)p0, a1 = (unsigned)(p0 >> 32);
          unsigned int a2 = (unsigned)p1, a3 = (unsigned)(p1 >> 32);
          if (a0 >= (unsigned)t && a1 >= (unsigned)t &&
              a2 >= (unsigned)t && a3 >= (unsigned)t) break;
          __builtin_amdgcn_s_sleep(1);
        }
        (void)__hip_atomic_load(fl, __ATOMIC_ACQUIRE, __HIP_MEMORY_SCOPE_AGENT);
      }
      __syncthreads();

      // ---- A-fragments from h_{t-1}: lane holds A[m=l15(+16)][k=ks*32+q4*8+j]
      const unsigned short* hp = hb_d + ((t - 1) & 1) * 8192 + q4 * 8;
      bf16x8 Af[2][8];
      #pragma unroll
      for (int mt = 0; mt < 2; ++mt)
        #pragma unroll
        for (int ks = 0; ks < 8; ++ks) {
          const ull_t* p = (const ull_t*)(hp + (size_t)(l15 + mt * 16) * 256 + ks * 32);
          union { ull_t u[2]; bf16x8 v; } cvt;
          cvt.u[0] = ld_ull(p);
          cvt.u[1] = ld_ull(p + 1);
          Af[mt][ks] = cvt.v;
        }
      #pragma unroll
      for (int q = 0; q < 4; ++q)
        #pragma unroll
        for (int mt = 0; mt < 2; ++mt) {
          f32x4 c = acc[q][mt];
          #pragma unroll
          for (int ks = 0; ks < 8; ++ks)
            c = __builtin_amdgcn_mfma_f32_16x16x32_bf16(Af[mt][ks], Bf[q][ks], c, 0, 0, 0);
          acc[q][mt] = c;
        }
    }

    // ---- activations; lane owns (b = q4*4+r+mt*16, hidx = j0w+l15)
    float hv[8];
    #pragma unroll
    for (int mt = 0; mt < 2; ++mt)
      #pragma unroll
      for (int r = 0; r < 4; ++r) {
        int ix = mt * 4 + r;
        float ig = sigf(acc[0][mt][r]);
        float fg = sigf(acc[1][mt][r]);
        float gg = tanhfast(acc[2][mt][r]);
        float og = sigf(acc[3][mt][r]);
        float c2 = fg * cst[ix] + ig * gg;
        cst[ix] = c2;
        hv[ix] = og * tanhfast(c2);
      }

    // ---- publish h_t (bf16, LLC-coherent), then flag, then outh (NT, keeps L2 clean)
    unsigned short* hc = hb_d + (t & 1) * 8192 + j0w + l15;
    #pragma unroll
    for (int mt = 0; mt < 2; ++mt)
      #pragma unroll
      for (int r = 0; r < 4; ++r)
        st_ushort(hc + (size_t)(q4 * 4 + r + mt * 16) * 256, f2bf(hv[mt * 4 + r]));
    __syncthreads();   // drains all waves' hbuf stores (vmcnt(0) before s_barrier)
    if (tid == 0) st_flag(fl + w, (unsigned)(t + 1));

    float* op = outh + (size_t)(s * 32) * 512 + d * 256 + j0w + l15;
    #pragma unroll
    for (int mt = 0; mt < 2; ++mt)
      #pragma unroll
      for (int r = 0; r < 4; ++r)
        __builtin_nontemporal_store(hv[mt * 4 + r], op + (size_t)(q4 * 4 + r + mt * 16) * 512);
  }
}

// ---------------------------------------------------------------- K5: emit GEMM (tiny)
__global__ __launch_bounds__(64) void k5_emit(
    const float* __restrict__ outh, const float* __restrict__ eW,
    const float* __restrict__ eb, float* __restrict__ em) {
  int row = blockIdx.x;
  int t = threadIdx.x;
  if (t < TT) {
    const float4* o4 = (const float4*)(outh + (size_t)row * 512);
    const float4* w4 = (const float4*)(eW + (size_t)t * 512);
    float acc = 0.f;
    #pragma unroll 16
    for (int k = 0; k < 128; ++k) {
      float4 a = o4[k], bq = w4[k];
      acc += a.x * bq.x + a.y * bq.y + a.z * bq.z + a.w * bq.w;
    }
    em[row * TT + t] = acc + eb[t];
  }
}

// ---------------------------------------------------------------- K6: CRF NLL (32 independent batches)
__global__ __launch_bounds__(64) void k6_crf(
    const int* __restrict__ sentence, const int* __restrict__ tags,
    const float* __restrict__ em, const float* __restrict__ trans,
    const float* __restrict__ startv, const float* __restrict__ endv,
    float* __restrict__ outp) {
  int b = blockIdx.x;
  int j = threadIdx.x;
  __shared__ float ash[TT];
  __shared__ float red[TT];
  float tc[TT];
  float alpha = 0.f;
  if (j < TT) {
    #pragma unroll
    for (int i = 0; i < TT; ++i) tc[i] = trans[i * TT + j];
    alpha = startv[j] + em[(0 * BB + b) * TT + j];
  }
  for (int s = 1; s < SS; ++s) {
    if (j < TT) ash[j] = alpha;
    __syncthreads();
    int m = (sentence[s * BB + b] != 1) ? 1 : 0;
    if (j < TT) {
      float mx = -1e30f;
      #pragma unroll
      for (int i = 0; i < TT; ++i) mx = fmaxf(mx, ash[i] + tc[i]);
      float sum = 0.f;
      #pragma unroll
      for (int i = 0; i < TT; ++i) sum += __expf(ash[i] + tc[i] - mx);
      float nxt = mx + __logf(sum) + em[(s * BB + b) * TT + j];
      if (m) alpha = nxt;
    }
    __syncthreads();
  }
  if (j < TT) red[j] = alpha + endv[j];
  __syncthreads();
  if (j == 0) {
    float mx = -1e30f;
    for (int i = 0; i < TT; ++i) mx = fmaxf(mx, red[i]);
    float sum = 0.f;
    for (int i = 0; i < TT; ++i) sum += __expf(red[i] - mx);
    float den = mx + __logf(sum);
    int prev = tags[0 * BB + b];
    float num = startv[prev] + em[(0 * BB + b) * TT + prev];
    for (int s = 1; s < SS; ++s) {
      int tg = tags[s * BB + b];
      if (sentence[s * BB + b] != 1) {
        num += trans[prev * TT + tg] + em[(s * BB + b) * TT + tg];
        prev = tg;
      }
    }
    num += endv[prev];
    atomicAdd(outp, den - num);
  }
}

// ---------------------------------------------------------------- launcher
extern "C" void kernel_launch(void* const* d_in, const int* in_sizes, int n_in,
                              void* d_out, int out_size, void* d_ws, size_t ws_size,
                              hipStream_t stream) {
  (void)in_sizes; (void)n_in; (void)out_size; (void)ws_size;
  const int*   sentence = (const int*)d_in[0];
  const int*   charidx  = (const int*)d_in[1];
  const int*   tags     = (const int*)d_in[2];
  const float* Wwe   = (const float*)d_in[3];
  const float* Wce   = (const float*)d_in[4];
  const float* cWihF = (const float*)d_in[5];
  const float* cWhhF = (const float*)d_in[6];
  const float* cbF   = (const float*)d_in[7];
  const float* wWihF = (const float*)d_in[8];
  const float* wWhhF = (const float*)d_in[9];
  const float* wbF   = (const float*)d_in[10];
  const float* cWihB = (const float*)d_in[11];
  const float* cWhhB = (const float*)d_in[12];
  const float* cbB   = (const float*)d_in[13];
  const float* wWihB = (const float*)d_in[14];
  const float* wWhhB = (const float*)d_in[15];
  const float* wbB   = (const float*)d_in[16];
  const float* eW    = (const float*)d_in[17];
  const float* eb    = (const float*)d_in[18];
  const float* trans = (const float*)d_in[19];
  const float* startv= (const float*)d_in[20];
  const float* endv  = (const float*)d_in[21];

  char* ws = (char*)d_ws;
  unsigned int*   flags = (unsigned int*)(ws + 0);        //     512 B
  float*          ihv   = (float*)(ws + 512);             //  204800 B
  float*          x     = (float*)(ws + 205312);          // 6291456 B
  float*          wg    = (float*)(ws + 6496768);         // 33554432 B
  unsigned short* hbuf  = (unsigned short*)(ws + 40051200); // 65536 B
  float*          outh  = (float*)(ws + 40116736);        // 8388608 B
  float*          em    = (float*)(ws + 48505344);        //  278528 B
  // total ws usage: 48,783,872 B

  hipMemsetAsync(flags, 0, 512, stream);
  hipMemsetAsync(d_out, 0, sizeof(float), stream);

  k0_ihvocab<<<200, 256, 0, stream>>>(Wce, cWihF, cbF, cWihB, cbB, ihv);
  k1_char<<<512, 256, 0, stream>>>(charidx, cWhhF, cWhhB, ihv, x);
  k2_we<<<4096, 64, 0, stream>>>(sentence, Wwe, x);
  k3_ihgemm<<<dim3(16, 32), 256, 0, stream>>>(x, wWihF, wbF, wWihB, wbB, wg);
  k4_word<<<8, 256, 0, stream>>>(wWhhF, wWhhB, wg, outh, hbuf, flags);
  k5_emit<<<4096, 64, 0, stream>>>(outh, eW, eb, em);
  k6_crf<<<32, 64, 0, stream>>>(sentence, tags, em, trans, startv, endv, (float*)d_out);
}

// Round 3
// 1010.461 us; speedup vs baseline: 3.2627x; 1.3017x over previous
//
#include <hip/hip_runtime.h>
#include <math.h>

#define SS 128
#define BB 32
#define CC 16
#define DW 256
#define DC 64
#define HC 128
#define KX 384   // DW + HC
#define TT 17

typedef __attribute__((ext_vector_type(8))) short bf16x8;
typedef __attribute__((ext_vector_type(4))) float f32x4;
typedef unsigned long long ull_t;

__device__ __forceinline__ float sigf(float x) { return 1.0f / (1.0f + __expf(-x)); }
__device__ __forceinline__ float tanhfast(float x) {
  float xc = fminf(fmaxf(x, -15.f), 15.f);
  float e = __expf(2.f * xc);
  return (e - 1.f) / (e + 1.f);
}
__device__ __forceinline__ unsigned short f2bf(float x) {
  unsigned int u = __float_as_uint(x);
  u += 0x7FFF + ((u >> 16) & 1);
  return (unsigned short)(u >> 16);
}
// Relaxed agent-scope atomics ONLY (native 32/64-bit, cache-bypassing; no fences).
__device__ __forceinline__ unsigned ld_u32(const unsigned* p) {
  return __hip_atomic_load(p, __ATOMIC_RELAXED, __HIP_MEMORY_SCOPE_AGENT);
}
__device__ __forceinline__ void st_u32(unsigned* p, unsigned v) {
  __hip_atomic_store(p, v, __ATOMIC_RELAXED, __HIP_MEMORY_SCOPE_AGENT);
}
__device__ __forceinline__ ull_t ld_ull(const ull_t* p) {
  return __hip_atomic_load(p, __ATOMIC_RELAXED, __HIP_MEMORY_SCOPE_AGENT);
}
__device__ __forceinline__ void st_ull(ull_t* p, ull_t v) {
  __hip_atomic_store(p, v, __ATOMIC_RELAXED, __HIP_MEMORY_SCOPE_AGENT);
}

// ---------------------------------------------------------------- K0: char ih vocab table
__global__ __launch_bounds__(256) void k0_ihvocab(
    const float* __restrict__ Wce,
    const float* __restrict__ WihF, const float* __restrict__ bF,
    const float* __restrict__ WihB, const float* __restrict__ bB,
    float* __restrict__ ihv) {
  int blk = blockIdx.x;          // 0..199
  int d = blk / 100, v = blk % 100;
  const float* Wih = d ? WihB : WihF;
  const float* bb  = d ? bB   : bF;
  __shared__ float ce[DC];
  if (threadIdx.x < DC) ce[threadIdx.x] = Wce[v * DC + threadIdx.x];
  __syncthreads();
  int g = threadIdx.x;
  float acc = bb[g];
  #pragma unroll 16
  for (int k = 0; k < DC; ++k) acc += ce[k] * Wih[g * DC + k];
  ihv[(d * 100 + v) * 256 + g] = acc;
}

// ---------------------------------------------------------------- K1: char BiLSTM (per-chain, no global sync)
__global__ __launch_bounds__(256) void k1_char(
    const int* __restrict__ charidx,   // (B,S,C)
    const float* __restrict__ WhhF, const float* __restrict__ WhhB,
    const float* __restrict__ ihv,     // (2,100,256)
    float* __restrict__ x)             // (4096, 384)
{
  int blk = blockIdx.x;
  int d = blk >> 8;
  int n0 = (blk & 255) * 16;
  const float* Whh = d ? WhhB : WhhF;

  __shared__ float Wl[256 * 68];
  __shared__ float hl[16 * 68];

  for (int i = threadIdx.x; i < 256 * 64; i += 256) {
    int g = i >> 6, k = i & 63;
    Wl[g * 68 + k] = Whh[i];
  }
  __syncthreads();

  int hh = threadIdx.x & 63;
  int ng = threadIdx.x >> 6;
  float c[4] = {0.f, 0.f, 0.f, 0.f};
  float h[4] = {0.f, 0.f, 0.f, 0.f};
  int bb_[4], ss_[4];
  #pragma unroll
  for (int m = 0; m < 4; ++m) {
    int n = n0 + ng + 4 * m;
    bb_[m] = n >> 7; ss_[m] = n & 127;
  }

  for (int t = 0; t < CC; ++t) {
    int cpos = d ? (CC - 1 - t) : t;
    float acc[4][4];
    #pragma unroll
    for (int m = 0; m < 4; ++m) {
      int v = charidx[bb_[m] * (SS * CC) + ss_[m] * CC + cpos];
      const float* base = ihv + (d * 100 + v) * 256 + hh;
      acc[m][0] = base[0]; acc[m][1] = base[64]; acc[m][2] = base[128]; acc[m][3] = base[192];
    }
    if (t > 0) {
      #pragma unroll 4
      for (int k = 0; k < 64; k += 4) {
        float4 w4[4];
        #pragma unroll
        for (int q = 0; q < 4; ++q)
          w4[q] = *(const float4*)&Wl[(q * 64 + hh) * 68 + k];
        #pragma unroll
        for (int m = 0; m < 4; ++m) {
          float4 h4 = *(const float4*)&hl[(ng + 4 * m) * 68 + k];
          #pragma unroll
          for (int q = 0; q < 4; ++q)
            acc[m][q] += h4.x * w4[q].x + h4.y * w4[q].y + h4.z * w4[q].z + h4.w * w4[q].w;
        }
      }
      __syncthreads();
    }
    #pragma unroll
    for (int m = 0; m < 4; ++m) {
      float ig = sigf(acc[m][0]);
      float fg = sigf(acc[m][1]);
      float gg = tanhfast(acc[m][2]);
      float og = sigf(acc[m][3]);
      c[m] = fg * c[m] + ig * gg;
      h[m] = og * tanhfast(c[m]);
      hl[(ng + 4 * m) * 68 + hh] = h[m];
    }
    __syncthreads();
  }
  #pragma unroll
  for (int m = 0; m < 4; ++m) {
    int row = ss_[m] * BB + bb_[m];
    x[row * KX + d * 64 + hh] = h[m];
  }
}

// ---------------------------------------------------------------- K2: word embedding gather
__global__ __launch_bounds__(64) void k2_we(
    const int* __restrict__ sentence, const float* __restrict__ Wwe,
    float* __restrict__ x) {
  int row = blockIdx.x;
  int idx = sentence[row];
  const float4* src = (const float4*)(Wwe + (size_t)idx * DW);
  float4* dst = (float4*)(x + (size_t)row * KX + HC);
  dst[threadIdx.x] = src[threadIdx.x];
}

// ---------------------------------------------------------------- K3: word ih GEMM  wg[d][row][g]
__global__ __launch_bounds__(256) void k3_ihgemm(
    const float* __restrict__ x,
    const float* __restrict__ WihF, const float* __restrict__ bF,
    const float* __restrict__ WihB, const float* __restrict__ bB,
    float* __restrict__ wg) {
  int n0 = blockIdx.x * 128;
  int m0 = blockIdx.y * 128;
  int d  = n0 >> 10;
  int gb = n0 & 1023;
  const float* Wih  = d ? WihB : WihF;
  const float* bias = d ? bB   : bF;

  __shared__ float At[32][132];
  __shared__ float Bt[32][132];

  int tid = threadIdx.x;
  int half = tid & 1, r = tid >> 1;
  int tm = tid & 15, tn = tid >> 4;
  float acc[8][8] = {};

  for (int k0 = 0; k0 < KX; k0 += 32) {
    __syncthreads();
    {
      const float4* srcA = (const float4*)(x + (size_t)(m0 + r) * KX + k0 + half * 16);
      const float4* srcB = (const float4*)(Wih + (size_t)(gb + r) * KX + k0 + half * 16);
      #pragma unroll
      for (int q = 0; q < 4; ++q) {
        float4 v = srcA[q];
        int kk = half * 16 + q * 4;
        At[kk + 0][r] = v.x; At[kk + 1][r] = v.y; At[kk + 2][r] = v.z; At[kk + 3][r] = v.w;
      }
      #pragma unroll
      for (int q = 0; q < 4; ++q) {
        float4 v = srcB[q];
        int kk = half * 16 + q * 4;
        Bt[kk + 0][r] = v.x; Bt[kk + 1][r] = v.y; Bt[kk + 2][r] = v.z; Bt[kk + 3][r] = v.w;
      }
    }
    __syncthreads();
    #pragma unroll 8
    for (int k = 0; k < 32; ++k) {
      float4 a0 = *(const float4*)&At[k][tm * 8];
      float4 a1 = *(const float4*)&At[k][tm * 8 + 4];
      float4 b0 = *(const float4*)&Bt[k][tn * 8];
      float4 b1 = *(const float4*)&Bt[k][tn * 8 + 4];
      float av[8] = {a0.x, a0.y, a0.z, a0.w, a1.x, a1.y, a1.z, a1.w};
      float bv[8] = {b0.x, b0.y, b0.z, b0.w, b1.x, b1.y, b1.z, b1.w};
      #pragma unroll
      for (int i = 0; i < 8; ++i)
        #pragma unroll
        for (int jq = 0; jq < 8; ++jq)
          acc[i][jq] += av[i] * bv[jq];
    }
  }
  float bv8[8];
  #pragma unroll
  for (int jq = 0; jq < 8; ++jq) bv8[jq] = bias[gb + tn * 8 + jq];
  #pragma unroll
  for (int i = 0; i < 8; ++i) {
    int m = m0 + tm * 8 + i;
    float* dst = wg + ((size_t)(d * 4096 + m)) * 1024 + gb + tn * 8;
    float4 v0 = {acc[i][0] + bv8[0], acc[i][1] + bv8[1], acc[i][2] + bv8[2], acc[i][3] + bv8[3]};
    float4 v1 = {acc[i][4] + bv8[4], acc[i][5] + bv8[5], acc[i][6] + bv8[6], acc[i][7] + bv8[7]};
    *(float4*)dst = v0; *(float4*)(dst + 4) = v1;
  }
}

// ---------------------------------------------------------------- K4: word BiLSTM recurrence
// 32 WGs x 64 threads (1 wave each), 16 waves per direction. Wave widx owns
// h-cols j0w..j0w+15 (x4 gate blocks). Whh in 128 VGPRs as bf16 B-frags.
// Protocol: relaxed 64-bit cache-bypassing atomics + per-wave tag words.
// NO barriers, NO fences, NO sub-32-bit atomics in the hot loop.
__global__ __launch_bounds__(64, 1) void k4_word(
    const float* __restrict__ WhhF, const float* __restrict__ WhhB,
    const float* __restrict__ wg,           // (2,4096,1024) f32
    float* __restrict__ outh,               // (4096,512) f32
    unsigned short* __restrict__ hbuf,      // (2 dir, 2 parity, 32 b, 256 k) bf16
    unsigned int* __restrict__ flags) {     // per dir: 16 tags at dir*16
  const int blk = blockIdx.x;               // 0..31
  const int d = blk >> 4, widx = blk & 15;
  const int l = threadIdx.x;                // 0..63
  const int l15 = l & 15, q4 = l >> 4;
  const int j0w = widx * 16;
  const float* __restrict__ Whh = d ? WhhB : WhhF;
  unsigned short* hb_d = hbuf + d * 16384;  // 2 parities * 8192
  unsigned int* fl = flags + d * 16;

  __shared__ unsigned short hl[32 * 24];    // per-wave transpose tile, row stride 48B

  // ---- Whh B-fragments resident: lane holds B[k=ks*32+q4*8+j][n=l15]
  bf16x8 Bf[4][8];
  #pragma unroll
  for (int q = 0; q < 4; ++q) {
    const float* wr = Whh + (size_t)(q * 256 + j0w + l15) * 256 + q4 * 8;
    #pragma unroll
    for (int ks = 0; ks < 8; ++ks) {
      float4 lo = *(const float4*)(wr + ks * 32);
      float4 hi = *(const float4*)(wr + ks * 32 + 4);
      bf16x8 f;
      f[0] = (short)f2bf(lo.x); f[1] = (short)f2bf(lo.y);
      f[2] = (short)f2bf(lo.z); f[3] = (short)f2bf(lo.w);
      f[4] = (short)f2bf(hi.x); f[5] = (short)f2bf(hi.y);
      f[6] = (short)f2bf(hi.z); f[7] = (short)f2bf(hi.w);
      Bf[q][ks] = f;
    }
  }

  float cst[8];
  #pragma unroll
  for (int i = 0; i < 8; ++i) cst[i] = 0.f;

  const int rb = l >> 1;          // transpose-read row (batch) 0..31
  const int rh = l & 1;           // transpose-read half-chunk

  for (int t = 0; t < SS; ++t) {
    const int s = d ? (SS - 1 - t) : t;

    // ---- ih gates into MFMA C-layout (issued before the wait; overlaps poll)
    f32x4 acc[4][2];
    const float* wgs = wg + ((size_t)d * 4096 + (size_t)s * 32) * 1024 + j0w + l15;
    #pragma unroll
    for (int q = 0; q < 4; ++q)
      #pragma unroll
      for (int mt = 0; mt < 2; ++mt)
        #pragma unroll
        for (int r = 0; r < 4; ++r)
          acc[q][mt][r] = wgs[(size_t)(q4 * 4 + r + mt * 16) * 1024 + q * 256];

    if (t > 0) {
      // ---- wait for all 16 producer waves of this direction (relaxed polls)
      for (;;) {
        unsigned tg = ld_u32(fl + l15);
        if (__all((int)(tg >= (unsigned)t))) break;
        __builtin_amdgcn_s_sleep(1);
      }

      // ---- A-fragments of h_{t-1}: cache-bypassing 8B loads
      const unsigned short* hp = hb_d + ((t - 1) & 1) * 8192 + q4 * 8;
      bf16x8 Af[2][8];
      #pragma unroll
      for (int mt = 0; mt < 2; ++mt)
        #pragma unroll
        for (int ks = 0; ks < 8; ++ks) {
          const ull_t* p = (const ull_t*)(hp + (size_t)(l15 + mt * 16) * 256 + ks * 32);
          union { ull_t u[2]; bf16x8 v; } cvt;
          cvt.u[0] = ld_ull(p);
          cvt.u[1] = ld_ull(p + 1);
          Af[mt][ks] = cvt.v;
        }
      #pragma unroll
      for (int q = 0; q < 4; ++q)
        #pragma unroll
        for (int mt = 0; mt < 2; ++mt) {
          f32x4 c = acc[q][mt];
          #pragma unroll
          for (int ks = 0; ks < 8; ++ks)
            c = __builtin_amdgcn_mfma_f32_16x16x32_bf16(Af[mt][ks], Bf[q][ks], c, 0, 0, 0);
          acc[q][mt] = c;
        }
    }

    // ---- activations; lane owns (b = q4*4+r+mt*16, col = j0w+l15)
    float hv[8];
    #pragma unroll
    for (int mt = 0; mt < 2; ++mt)
      #pragma unroll
      for (int r = 0; r < 4; ++r) {
        int ix = mt * 4 + r;
        float ig = sigf(acc[0][mt][r]);
        float fg = sigf(acc[1][mt][r]);
        float gg = tanhfast(acc[2][mt][r]);
        float og = sigf(acc[3][mt][r]);
        float c2 = fg * cst[ix] + ig * gg;
        cst[ix] = c2;
        hv[ix] = og * tanhfast(c2);
      }

    // ---- wave-local LDS transpose: [b][col] tile, then 8B-aligned publish
    #pragma unroll
    for (int mt = 0; mt < 2; ++mt)
      #pragma unroll
      for (int r = 0; r < 4; ++r)
        hl[(q4 * 4 + r + mt * 16) * 24 + l15] = f2bf(hv[mt * 4 + r]);
    // lane reads 16B contiguous of row rb (cols j0w + rh*8 .. +7); wave-local,
    // ordered by lgkmcnt (no barrier needed: single wave).
    ull_t plo = *(const ull_t*)&hl[rb * 24 + rh * 8];
    ull_t phi = *(const ull_t*)&hl[rb * 24 + rh * 8 + 4];
    ull_t* dst = (ull_t*)(hb_d + (t & 1) * 8192 + (size_t)rb * 256 + j0w + rh * 8);
    st_ull(dst, plo);
    st_ull(dst + 1, phi);
    // drain THIS wave's publish stores, then tag (relaxed; no fence)
    asm volatile("s_waitcnt vmcnt(0)" ::: "memory");
    if (l == 0) st_u32(fl + widx, (unsigned)(t + 1));

    // ---- outh (non-temporal, off critical path)
    float* op = outh + (size_t)(s * 32) * 512 + d * 256 + j0w + l15;
    #pragma unroll
    for (int mt = 0; mt < 2; ++mt)
      #pragma unroll
      for (int r = 0; r < 4; ++r)
        __builtin_nontemporal_store(hv[mt * 4 + r], op + (size_t)(q4 * 4 + r + mt * 16) * 512);
  }
}

// ---------------------------------------------------------------- K5: emit GEMM (tiny)
__global__ __launch_bounds__(64) void k5_emit(
    const float* __restrict__ outh, const float* __restrict__ eW,
    const float* __restrict__ eb, float* __restrict__ em) {
  int row = blockIdx.x;
  int t = threadIdx.x;
  if (t < TT) {
    const float4* o4 = (const float4*)(outh + (size_t)row * 512);
    const float4* w4 = (const float4*)(eW + (size_t)t * 512);
    float acc = 0.f;
    #pragma unroll 16
    for (int k = 0; k < 128; ++k) {
      float4 a = o4[k], bq = w4[k];
      acc += a.x * bq.x + a.y * bq.y + a.z * bq.z + a.w * bq.w;
    }
    em[row * TT + t] = acc + eb[t];
  }
}

// ---------------------------------------------------------------- K6: CRF NLL (32 independent batches)
__global__ __launch_bounds__(64) void k6_crf(
    const int* __restrict__ sentence, const int* __restrict__ tags,
    const float* __restrict__ em, const float* __restrict__ trans,
    const float* __restrict__ startv, const float* __restrict__ endv,
    float* __restrict__ outp) {
  int b = blockIdx.x;
  int j = threadIdx.x;
  __shared__ float ash[TT];
  __shared__ float red[TT];
  float tc[TT];
  float alpha = 0.f;
  if (j < TT) {
    #pragma unroll
    for (int i = 0; i < TT; ++i) tc[i] = trans[i * TT + j];
    alpha = startv[j] + em[(0 * BB + b) * TT + j];
  }
  for (int s = 1; s < SS; ++s) {
    if (j < TT) ash[j] = alpha;
    __syncthreads();
    int m = (sentence[s * BB + b] != 1) ? 1 : 0;
    if (j < TT) {
      float mx = -1e30f;
      #pragma unroll
      for (int i = 0; i < TT; ++i) mx = fmaxf(mx, ash[i] + tc[i]);
      float sum = 0.f;
      #pragma unroll
      for (int i = 0; i < TT; ++i) sum += __expf(ash[i] + tc[i] - mx);
      float nxt = mx + __logf(sum) + em[(s * BB + b) * TT + j];
      if (m) alpha = nxt;
    }
    __syncthreads();
  }
  if (j < TT) red[j] = alpha + endv[j];
  __syncthreads();
  if (j == 0) {
    float mx = -1e30f;
    for (int i = 0; i < TT; ++i) mx = fmaxf(mx, red[i]);
    float sum = 0.f;
    for (int i = 0; i < TT; ++i) sum += __expf(red[i] - mx);
    float den = mx + __logf(sum);
    int prev = tags[0 * BB + b];
    float num = startv[prev] + em[(0 * BB + b) * TT + prev];
    for (int s = 1; s < SS; ++s) {
      int tg = tags[s * BB + b];
      if (sentence[s * BB + b] != 1) {
        num += trans[prev * TT + tg] + em[(s * BB + b) * TT + tg];
        prev = tg;
      }
    }
    num += endv[prev];
    atomicAdd(outp, den - num);
  }
}

// ---------------------------------------------------------------- launcher
extern "C" void kernel_launch(void* const* d_in, const int* in_sizes, int n_in,
                              void* d_out, int out_size, void* d_ws, size_t ws_size,
                              hipStream_t stream) {
  (void)in_sizes; (void)n_in; (void)out_size; (void)ws_size;
  const int*   sentence = (const int*)d_in[0];
  const int*   charidx  = (const int*)d_in[1];
  const int*   tags     = (const int*)d_in[2];
  const float* Wwe   = (const float*)d_in[3];
  const float* Wce   = (const float*)d_in[4];
  const float* cWihF = (const float*)d_in[5];
  const float* cWhhF = (const float*)d_in[6];
  const float* cbF   = (const float*)d_in[7];
  const float* wWihF = (const float*)d_in[8];
  const float* wWhhF = (const float*)d_in[9];
  const float* wbF   = (const float*)d_in[10];
  const float* cWihB = (const float*)d_in[11];
  const float* cWhhB = (const float*)d_in[12];
  const float* cbB   = (const float*)d_in[13];
  const float* wWihB = (const float*)d_in[14];
  const float* wWhhB = (const float*)d_in[15];
  const float* wbB   = (const float*)d_in[16];
  const float* eW    = (const float*)d_in[17];
  const float* eb    = (const float*)d_in[18];
  const float* trans = (const float*)d_in[19];
  const float* startv= (const float*)d_in[20];
  const float* endv  = (const float*)d_in[21];

  char* ws = (char*)d_ws;
  unsigned int*   flags = (unsigned int*)(ws + 0);        //     512 B
  float*          ihv   = (float*)(ws + 512);             //  204800 B
  float*          x     = (float*)(ws + 205312);          // 6291456 B
  float*          wg    = (float*)(ws + 6496768);         // 33554432 B
  unsigned short* hbuf  = (unsigned short*)(ws + 40051200); // 65536 B
  float*          outh  = (float*)(ws + 40116736);        // 8388608 B
  float*          em    = (float*)(ws + 48505344);        //  278528 B
  // total ws usage: 48,783,872 B

  hipMemsetAsync(flags, 0, 512, stream);
  hipMemsetAsync(d_out, 0, sizeof(float), stream);

  k0_ihvocab<<<200, 256, 0, stream>>>(Wce, cWihF, cbF, cWihB, cbB, ihv);
  k1_char<<<512, 256, 0, stream>>>(charidx, cWhhF, cWhhB, ihv, x);
  k2_we<<<4096, 64, 0, stream>>>(sentence, Wwe, x);
  k3_ihgemm<<<dim3(16, 32), 256, 0, stream>>>(x, wWihF, wbF, wWihB, wbB, wg);
  k4_word<<<32, 64, 0, stream>>>(wWhhF, wWhhB, wg, outh, hbuf, flags);
  k5_emit<<<4096, 64, 0, stream>>>(outh, eW, eb, em);
  k6_crf<<<32, 64, 0, stream>>>(sentence, tags, em, trans, startv, endv, (float*)d_out);
}